// Round 5
// baseline (100.587 us; speedup 1.0000x reference)
//
#include <hip/hip_runtime.h>

// B=4, M=8, N=128, D=32, K=2D=H=64
#define NNC 128
#define DDC 32
#define KKC 64
constexpr int ND = NNC * DDC;   // 4096 floats per (b,m)
#define SMALLV 1e-8f

__device__ __forceinline__ float gelu_f(float v) {
    // tanh-gelu folded: gelu(v) = v - v * rcp(1 + exp2(v*(a*v^2+b)))
    float v2 = v * v;
    float p  = fmaf(0.1029432f, v2, 2.3022082f);
    float e  = __builtin_amdgcn_exp2f(v * p);
    float r  = __builtin_amdgcn_rcpf(e + 1.0f);
    return fmaf(-v, r, v);
}

// ===========================================================================
// ONE ordinary kernel. Grid = 256 blocks = bm(32) x jt(8 tiles of 16 j),
// 1024 threads/block (16 waves -> 4 waves/SIMD; round-4 ran 2 waves/SIMD and
// was latency-exposed on the trans/ds chains).
//
// LDS arena: 16384 floats (64 KB), lifetime-overlaid (floats):
//   0      sX1   [128][32]  4096
//   4096   sA1   [128][68]  8704  (ends 12800); overlays, dead before A1:
//            sXn  @4096 [128][32] (ends 8192)
//            sH64 @8192 [64][64]  (ends 12288)
//   12800  sA2t  [16][68]   1088  ([j][k] row-major, b128 along k)
//   13888  sSt   [16][132]  2112  ([j][i], b128 along i in aggregation)
//            overlay (dead before sSt written): scr @13888 [1024]
//   16000  sV2[64], 16064 sAny[128], 16192 sRed[16], 16208 sC3[1]
// Weight columns register-cached per phase (scoped to keep VGPR <= 128):
// colA=W1a[:,k], colB=W1b[:,dL], colC=W2a[:,k].
// ===========================================================================
__global__ __launch_bounds__(1024, 4) void fused4(
    const float* __restrict__ x, const float* __restrict__ x_size,
    const float* __restrict__ W1a, const float* __restrict__ b1a,
    const float* __restrict__ W1b, const float* __restrict__ b1b,
    const float* __restrict__ W2a, const float* __restrict__ b2a,
    const float* __restrict__ W2b, const float* __restrict__ b2b,
    const float* __restrict__ w3, const float* __restrict__ b3,
    float* __restrict__ out)
{
    __shared__ __align__(16) float smem[16384];

    const int t   = threadIdx.x;
    const int blk = blockIdx.x;
    const int bm  = blk >> 3;
    const int jt  = blk & 7;
    const int k   = t & 63;
    const int w   = t >> 6;        // wave id 0..15
    const int dL  = t & 31;

    const int iN = (int)(x_size[bm >> 3] + 0.5f);

    float* sX1  = smem;
    float* sA1  = smem + 4096;
    float* sXn  = smem + 4096;     // overlay: dead before sA1 writes
    float* sH64 = smem + 8192;     // overlay: dead before sA1 writes
    float* sA2t = smem + 12800;    // [16][68]
    float* sSt  = smem + 13888;    // [16][132]
    float* scr  = smem + 13888;    // v2 partial scratch (dead before sSt)
    float* sV2  = smem + 16000;
    float* sAny = smem + 16064;
    float* sRed = smem + 16192;
    float* sC3  = smem + 16208;

    // ---- fully-invalid j-tile: write zeros, done (block-uniform) ----
    if (jt * 16 >= iN) {
        if (t < 512) out[(size_t)bm * ND + jt * 512 + t] = 0.f;
        return;
    }

    const float rb1a = b1a[k];
    const float rb1b = b1b[dL];
    const float rb2a = b2a[k];

    {   // v2 partials: v2[kk] = sum_h W2b[kk][h]*w3[h]; 16-way split
        const int kk = t >> 4, hq = t & 15;
        float p = 0.f;
        #pragma unroll
        for (int h = 0; h < 4; ++h)
            p = fmaf(W2b[kk * 64 + hq * 4 + h], w3[hq * 4 + h], p);
        scr[t] = p;
    }
    if (t < 64) {                         // c3 = sum_h b2b[h]*w3[h]
        float q = b2b[t] * w3[t];
        #pragma unroll
        for (int off = 32; off; off >>= 1) q += __shfl_xor(q, off);
        if (t == 0) sC3[0] = q;
    }
    if (t < 128) sAny[t] = 0.f;
    __syncthreads();                                   // A

    // ---- stats over x[bm]; each thread holds 1 float4 ----
    const float4* xs4 = (const float4*)(x + (size_t)bm * ND);
    float4 xv4 = xs4[t];
    float lsum = xv4.x + xv4.y + xv4.z + xv4.w;
    if (xv4.x != 0.f || xv4.y != 0.f || xv4.z != 0.f || xv4.w != 0.f)
        sAny[t >> 3] = 1.f;
    #pragma unroll
    for (int off = 32; off; off >>= 1) lsum += __shfl_xor(lsum, off);
    if ((t & 63) == 0) sRed[w] = lsum;
    __syncthreads();                                   // B
    if (t < 64) {                                      // finalize v2
        float vp = 0.f;
        #pragma unroll
        for (int q = 0; q < 16; ++q) vp += scr[t * 16 + q];
        sV2[t] = vp;
    }
    const float denom = x_size[bm >> 3] * 32.f;
    float mean = 0.f;
    #pragma unroll
    for (int r = 0; r < 16; ++r) mean += sRed[r];
    mean /= denom;

    float lsq;
    {
        const float mk = sAny[t >> 3];
        const float dx = xv4.x - mean, dy = xv4.y - mean;
        const float dz = xv4.z - mean, dw = xv4.w - mean;
        lsq = mk * (dx * dx + dy * dy + dz * dz + dw * dw);
    }
    #pragma unroll
    for (int off = 32; off; off >>= 1) lsq += __shfl_xor(lsq, off);
    __syncthreads();                                   // C (sRed WAR)
    if ((t & 63) == 0) sRed[w] = lsq;
    __syncthreads();                                   // D
    float sq = 0.f;
    #pragma unroll
    for (int r = 0; r < 16; ++r) sq += sRed[r];
    const float inv = 1.f / (sqrtf(sq / denom) + SMALLV);

    // ---- normalize -> sXn ----
    {
        const float mk = sAny[t >> 3] * inv;
        float4 q = xv4;
        q.x = (q.x - mean) * mk; q.y = (q.y - mean) * mk;
        q.z = (q.z - mean) * mk; q.w = (q.w - mean) * mk;
        ((float4*)sXn)[t] = q;
    }
    __syncthreads();                                   // E

    // ---- MLP1 in 2 chunks of 64 rows ----
    for (int c = 0; c < 2; ++c) {
        const int rb = c * 64;
        const bool live = (rb < iN);
        {   // H = gelu(xn@W1a + b1a): rows w + 16r, r<4; col k
            float colA[32];
            #pragma unroll
            for (int d = 0; d < 32; ++d) colA[d] = W1a[d * 64 + k];
            if (live) {
                #pragma unroll
                for (int r = 0; r < 4; ++r) {
                    const int nl = w + 16 * r;
                    const float4* xr4 = (const float4*)&sXn[(rb + nl) * 32];
                    float acc = rb1a;
                    #pragma unroll
                    for (int dq = 0; dq < 8; ++dq) {
                        float4 xv = xr4[dq];
                        acc = fmaf(xv.x, colA[4 * dq + 0], acc);
                        acc = fmaf(xv.y, colA[4 * dq + 1], acc);
                        acc = fmaf(xv.z, colA[4 * dq + 2], acc);
                        acc = fmaf(xv.w, colA[4 * dq + 3], acc);
                    }
                    sH64[nl * 64 + k] = gelu_f(acc);
                }
            }
        }
        __syncthreads();                               // F_c
        {   // x1 = (H@W1b + b1b)*mask: rows (t>>5) + 32p, p<2; col dL
            float colB[64];
            #pragma unroll
            for (int q2 = 0; q2 < 64; ++q2) colB[q2] = W1b[q2 * 32 + dL];
            if (live) {
                #pragma unroll
                for (int p = 0; p < 2; ++p) {
                    const int nl = (t >> 5) + 32 * p;
                    const float4* hr4 = (const float4*)&sH64[nl * 64];
                    float acc = rb1b;
                    #pragma unroll
                    for (int qq = 0; qq < 16; ++qq) {
                        float4 hv = hr4[qq];
                        acc = fmaf(hv.x, colB[4 * qq + 0], acc);
                        acc = fmaf(hv.y, colB[4 * qq + 1], acc);
                        acc = fmaf(hv.z, colB[4 * qq + 2], acc);
                        acc = fmaf(hv.w, colB[4 * qq + 3], acc);
                    }
                    sX1[(rb + nl) * 32 + dL] = acc * sAny[rb + nl];
                }
            } else {
                #pragma unroll
                for (int p = 0; p < 2; ++p)
                    sX1[(rb + (t >> 5) + 32 * p) * 32 + dL] = 0.f;
            }
        }
        __syncthreads();                               // G_c
    }

    // ---- A2t[j][k] = xn_j @ W2a: wave w owns row j=w (16 rows x 64 cols) ----
    float colC[32];
    #pragma unroll
    for (int d = 0; d < 32; ++d) colC[d] = W2a[d * 64 + k];
    {
        const float4* xr4 = (const float4*)&sXn[(jt * 16 + w) * 32];
        float acc = 0.f;
        #pragma unroll
        for (int dq = 0; dq < 8; ++dq) {
            float4 xv = xr4[dq];
            acc = fmaf(xv.x, colC[4 * dq + 0], acc);
            acc = fmaf(xv.y, colC[4 * dq + 1], acc);
            acc = fmaf(xv.z, colC[4 * dq + 2], acc);
            acc = fmaf(xv.w, colC[4 * dq + 3], acc);
        }
        sA2t[w * 68 + k] = acc;
    }
    __syncthreads();                                   // H (xn/H64 dead now)

    // ---- A1 = x1 @ W2a + b2a (overwrites xn/H region) ----
    const int ICAP = (iN + 3) & ~3;
    for (int n = w; n < ICAP; n += 16) {
        const float4* x14 = (const float4*)&sX1[n * 32];
        float acc = rb2a;
        #pragma unroll
        for (int dq = 0; dq < 8; ++dq) {
            float4 xv = x14[dq];
            acc = fmaf(xv.x, colC[4 * dq + 0], acc);
            acc = fmaf(xv.y, colC[4 * dq + 1], acc);
            acc = fmaf(xv.z, colC[4 * dq + 2], acc);
            acc = fmaf(xv.w, colC[4 * dq + 3], acc);
        }
        sA1[n * 68 + k] = acc;
    }
    __syncthreads();                                   // I

    // ---- S-phase: thread = (j = t&15, i0 = 2*(t>>4)); all-b128 operands ----
    {
        const float c3 = sC3[0];
        const int j  = t & 15;
        const int i0 = (t >> 4) * 2;
        if (i0 < ICAP) {
            float a0 = c3, a1 = c3;
            const float* a2row = &sA2t[j * 68];
            const float* b0r = &sA1[(i0 + 0) * 68];
            const float* b1r = &sA1[(i0 + 1) * 68];
            #pragma unroll 4
            for (int kk = 0; kk < 64; kk += 4) {
                float4 va = *(const float4*)&a2row[kk];
                float4 vv = *(const float4*)&sV2[kk];
                float4 q0 = *(const float4*)&b0r[kk];
                float4 q1 = *(const float4*)&b1r[kk];
                a0 = fmaf(gelu_f(q0.x - va.x), vv.x, a0);
                a1 = fmaf(gelu_f(q1.x - va.x), vv.x, a1);
                a0 = fmaf(gelu_f(q0.y - va.y), vv.y, a0);
                a1 = fmaf(gelu_f(q1.y - va.y), vv.y, a1);
                a0 = fmaf(gelu_f(q0.z - va.z), vv.z, a0);
                a1 = fmaf(gelu_f(q1.z - va.z), vv.z, a1);
                a0 = fmaf(gelu_f(q0.w - va.w), vv.w, a0);
                a1 = fmaf(gelu_f(q1.w - va.w), vv.w, a1);
            }
            *(float2*)&sSt[j * 132 + i0] = make_float2(a0, a1);
        }
    }
    __syncthreads();                                   // J

    // ---- aggregate + b3 + residual, mask, write out (t<512, 1 out each) ----
    if (t < 512) {
        const int jA = t >> 5;         // 0..15
        const int dA = t & 31;
        const float* strow = &sSt[jA * 132];
        float s0 = 0.f;
        for (int i = 0; i < ICAP; i += 4) {
            float4 sv = *(const float4*)&strow[i];
            s0 = fmaf(sv.x, sX1[(i + 0) * 32 + dA], s0);
            s0 = fmaf(sv.y, sX1[(i + 1) * 32 + dA], s0);
            s0 = fmaf(sv.z, sX1[(i + 2) * 32 + dA], s0);
            s0 = fmaf(sv.w, sX1[(i + 3) * 32 + dA], s0);
        }
        const int jg = jt * 16 + jA;
        const float msk = sAny[jg];
        const size_t ob = (size_t)bm * ND + jg * 32 + dA;
        out[ob] = (s0 + b3[0] + x[ob]) * msk;
    }
}

extern "C" void kernel_launch(void* const* d_in, const int* in_sizes, int n_in,
                              void* d_out, int out_size, void* d_ws, size_t ws_size,
                              hipStream_t stream) {
    (void)in_sizes; (void)n_in; (void)d_ws; (void)ws_size; (void)out_size;
    const float* x      = (const float*)d_in[0];
    const float* x_size = (const float*)d_in[1];
    const float* W1a    = (const float*)d_in[2];
    const float* b1a    = (const float*)d_in[3];
    const float* W1b    = (const float*)d_in[4];
    const float* b1b    = (const float*)d_in[5];
    const float* W2a    = (const float*)d_in[6];
    const float* b2a    = (const float*)d_in[7];
    const float* W2b    = (const float*)d_in[8];
    const float* b2b    = (const float*)d_in[9];
    const float* w3     = (const float*)d_in[10];
    const float* b3     = (const float*)d_in[11];
    float* out = (float*)d_out;

    fused4<<<dim3(256), dim3(1024), 0, stream>>>(
        x, x_size, W1a, b1a, W1b, b1b, W2a, b2a, W2b, b2b, w3, b3, out);
}

// Round 6
// 98.428 us; speedup vs baseline: 1.0219x; 1.0219x over previous
//
#include <hip/hip_runtime.h>

// B=4, M=8, N=128, D=32, K=2D=H=64
#define NNC 128
#define DDC 32
#define KKC 64
constexpr int ND = NNC * DDC;   // 4096 floats per (b,m)
#define SMALLV 1e-8f

__device__ __forceinline__ float gelu_f(float v) {
    // tanh-gelu folded: gelu(v) = v - v * rcp(1 + exp2(v*(a*v^2+b)))
    float v2 = v * v;
    float p  = fmaf(0.1029432f, v2, 2.3022082f);
    float e  = __builtin_amdgcn_exp2f(v * p);
    float r  = __builtin_amdgcn_rcpf(e + 1.0f);
    return fmaf(-v, r, v);
}

// ===========================================================================
// ONE ordinary kernel. Grid = 512 blocks = bm(32) x jt(8) x ih(2 i-halves),
// 512 threads (8 waves). TWO blocks per CU => two independent barrier
// domains: one block's compute hides the other's barrier drains (rounds 4/5
// showed a single barrier domain is the limiter, not wave count).
//
// Each block: stats (redundant) + MLP1/A1 for its 64 i-rows only + A2 for
// its 16 j + S[64i x 16j] + partial aggregation. Output via atomicAdd onto
// the harness-zeroed out buffer; ih=0 adds the b3 + residual term.
//
// LDS 12640 floats (49.4 KB) -> 2 blocks/CU (98.8 KB <= 160 KB). Overlays:
//   0      sX1  [64][32]  2048
//   2048   sA1  [64][68]  4352   overlays (dead before A1 written):
//            sXn @2048 [128][32] 4096, sH @6144 [64][64] 4096 (ends 10240)
//   10240  sA2t [16][68]  1088
//   11328  sSt  [16][68]  1088   overlay: scr[512] (v2 partials, dead first)
//   12416  sV2[64] 12480 sAny[128] 12608 sRed[8] 12616 sC3[1]
// __launch_bounds__(512,4): 16 waves/CU = 4/SIMD -> VGPR <= 128; weight
// column caches are phase-scoped to fit.
// ===========================================================================
__global__ __launch_bounds__(512, 4) void fused6(
    const float* __restrict__ x, const float* __restrict__ x_size,
    const float* __restrict__ W1a, const float* __restrict__ b1a,
    const float* __restrict__ W1b, const float* __restrict__ b1b,
    const float* __restrict__ W2a, const float* __restrict__ b2a,
    const float* __restrict__ W2b, const float* __restrict__ b2b,
    const float* __restrict__ w3, const float* __restrict__ b3,
    float* __restrict__ out)
{
    __shared__ __align__(16) float smem[12640];

    const int t   = threadIdx.x;
    const int blk = blockIdx.x;
    const int bm  = blk >> 4;
    const int jt  = (blk >> 1) & 7;
    const int ih  = blk & 1;
    const int k   = t & 63;
    const int w   = t >> 6;        // wave 0..7
    const int dL  = t & 31;

    const int iN = (int)(x_size[bm >> 3] + 0.5f);

    // out is zeroed by the harness before each launch; masked/invalid
    // positions stay 0, so fully-invalid blocks just exit.
    if (jt * 16 >= iN) return;     // (iN >= 64 so jt 0..3 always valid)
    if (ih * 64 >= iN) return;

    float* sX1  = smem;            // [64][32]
    float* sA1  = smem + 2048;     // [64][68]
    float* sXn  = smem + 2048;     // [128][32] overlay
    float* sH   = smem + 6144;     // [64][64]  overlay
    float* sA2t = smem + 10240;    // [16][68]
    float* sSt  = smem + 11328;    // [16][68]
    float* scr  = smem + 11328;    // v2 partials (dead before sSt)
    float* sV2  = smem + 12416;
    float* sAny = smem + 12480;
    float* sRed = smem + 12608;
    float* sC3  = smem + 12616;

    const float rb1a = b1a[k];
    const float rb1b = b1b[dL];
    const float rb2a = b2a[k];

    {   // v2 partials: v2[kk] = sum_h W2b[kk][h]*w3[h]; 8-way split
        const int kk = t >> 3, hq = t & 7;
        float p = 0.f;
        #pragma unroll
        for (int h = 0; h < 8; ++h)
            p = fmaf(W2b[kk * 64 + hq * 8 + h], w3[hq * 8 + h], p);
        scr[t] = p;
    }
    if (t < 64) {                  // c3 = sum_h b2b[h]*w3[h]
        float q = b2b[t] * w3[t];
        #pragma unroll
        for (int off = 32; off; off >>= 1) q += __shfl_xor(q, off);
        if (t == 0) sC3[0] = q;
    }
    if (t < 128) sAny[t] = 0.f;
    __syncthreads();                                   // A

    // ---- stats over x[bm]; 2 float4 per thread ----
    const float4* xs4 = (const float4*)(x + (size_t)bm * ND);
    float4 v4[2];
    float lsum = 0.f;
    #pragma unroll
    for (int s = 0; s < 2; ++s) {
        int f = t + s * 512;
        float4 q = xs4[f];
        v4[s] = q;
        lsum += q.x + q.y + q.z + q.w;
        if (q.x != 0.f || q.y != 0.f || q.z != 0.f || q.w != 0.f) sAny[f >> 3] = 1.f;
    }
    #pragma unroll
    for (int off = 32; off; off >>= 1) lsum += __shfl_xor(lsum, off);
    if ((t & 63) == 0) sRed[w] = lsum;
    __syncthreads();                                   // B
    if (t < 64) {                                      // finalize v2
        float vp = 0.f;
        #pragma unroll
        for (int q = 0; q < 8; ++q) vp += scr[t * 8 + q];
        sV2[t] = vp;
    }
    const float denom = x_size[bm >> 3] * 32.f;
    float mean = 0.f;
    #pragma unroll
    for (int r = 0; r < 8; ++r) mean += sRed[r];
    mean /= denom;

    float lsq = 0.f;
    #pragma unroll
    for (int s = 0; s < 2; ++s) {
        int f = t + s * 512;
        float mk = sAny[f >> 3];
        float dx = v4[s].x - mean, dy = v4[s].y - mean;
        float dz = v4[s].z - mean, dw = v4[s].w - mean;
        lsq += mk * (dx * dx + dy * dy + dz * dz + dw * dw);
    }
    #pragma unroll
    for (int off = 32; off; off >>= 1) lsq += __shfl_xor(lsq, off);
    __syncthreads();                                   // C (sRed WAR)
    if ((t & 63) == 0) sRed[w] = lsq;
    __syncthreads();                                   // D
    float sq = 0.f;
    #pragma unroll
    for (int r = 0; r < 8; ++r) sq += sRed[r];
    const float inv = 1.f / (sqrtf(sq / denom) + SMALLV);

    // ---- normalize -> sXn (all 128 rows; H needs ih-half, A2t needs jt rows) ----
    #pragma unroll
    for (int s = 0; s < 2; ++s) {
        int f = t + s * 512;
        float mk = sAny[f >> 3] * inv;
        float4 q = v4[s];
        q.x = (q.x - mean) * mk; q.y = (q.y - mean) * mk;
        q.z = (q.z - mean) * mk; q.w = (q.w - mean) * mk;
        ((float4*)sXn)[f] = q;
    }
    __syncthreads();                                   // E

    // ---- phase: H (own 64 i-rows) + A2t (own 16 j-rows) ----
    {
        float colA[32], colC[32];
        #pragma unroll
        for (int d = 0; d < 32; ++d) colA[d] = W1a[d * 64 + k];
        #pragma unroll
        for (int d = 0; d < 32; ++d) colC[d] = W2a[d * 64 + k];
        // H = gelu(xn@W1a + b1a): wave w -> local rows w*8..w*8+7
        #pragma unroll
        for (int rr = 0; rr < 8; ++rr) {
            const int nl = w * 8 + rr;
            const float4* xr4 = (const float4*)&sXn[(ih * 64 + nl) * 32];
            float acc = rb1a;
            #pragma unroll
            for (int dq = 0; dq < 8; ++dq) {
                float4 xv = xr4[dq];
                acc = fmaf(xv.x, colA[4 * dq + 0], acc);
                acc = fmaf(xv.y, colA[4 * dq + 1], acc);
                acc = fmaf(xv.z, colA[4 * dq + 2], acc);
                acc = fmaf(xv.w, colA[4 * dq + 3], acc);
            }
            sH[nl * 64 + k] = gelu_f(acc);
        }
        // A2t[j][k] = xn_j @ W2a: wave w -> j-local w*2, w*2+1
        #pragma unroll
        for (int q = 0; q < 2; ++q) {
            const int jl = w * 2 + q;
            const float4* xr4 = (const float4*)&sXn[(jt * 16 + jl) * 32];
            float acc = 0.f;
            #pragma unroll
            for (int dq = 0; dq < 8; ++dq) {
                float4 xv = xr4[dq];
                acc = fmaf(xv.x, colC[4 * dq + 0], acc);
                acc = fmaf(xv.y, colC[4 * dq + 1], acc);
                acc = fmaf(xv.z, colC[4 * dq + 2], acc);
                acc = fmaf(xv.w, colC[4 * dq + 3], acc);
            }
            sA2t[jl * 68 + k] = acc;
        }
    }
    __syncthreads();                                   // F

    // ---- x1 = (H@W1b + b1b)*mask for own 64 rows ----
    {
        float colB[64];
        #pragma unroll
        for (int q2 = 0; q2 < 64; ++q2) colB[q2] = W1b[q2 * 32 + dL];
        #pragma unroll
        for (int p = 0; p < 4; ++p) {
            const int nl = (t >> 5) + 16 * p;
            const float4* hr4 = (const float4*)&sH[nl * 64];
            float acc = rb1b;
            #pragma unroll
            for (int qq = 0; qq < 16; ++qq) {
                float4 hv = hr4[qq];
                acc = fmaf(hv.x, colB[4 * qq + 0], acc);
                acc = fmaf(hv.y, colB[4 * qq + 1], acc);
                acc = fmaf(hv.z, colB[4 * qq + 2], acc);
                acc = fmaf(hv.w, colB[4 * qq + 3], acc);
            }
            sX1[nl * 32 + dL] = acc * sAny[ih * 64 + nl];
        }
    }
    __syncthreads();                                   // G (sXn/sH dead now)

    // ---- A1 = x1 @ W2a + b2a (own 64 rows; overwrites sXn/sH region) ----
    {
        float colC[32];
        #pragma unroll
        for (int d = 0; d < 32; ++d) colC[d] = W2a[d * 64 + k];
        #pragma unroll
        for (int r = 0; r < 8; ++r) {
            const int nl = w + 8 * r;
            const float4* x14 = (const float4*)&sX1[nl * 32];
            float acc = rb2a;
            #pragma unroll
            for (int dq = 0; dq < 8; ++dq) {
                float4 xv = x14[dq];
                acc = fmaf(xv.x, colC[4 * dq + 0], acc);
                acc = fmaf(xv.y, colC[4 * dq + 1], acc);
                acc = fmaf(xv.z, colC[4 * dq + 2], acc);
                acc = fmaf(xv.w, colC[4 * dq + 3], acc);
            }
            sA1[nl * 68 + k] = acc;
        }
    }
    __syncthreads();                                   // H

    // ---- S-phase: thread = (j = t&15, i0 = 2*(t>>4)); all-b128 operands ----
    {
        const float c3 = sC3[0];
        const int j  = t & 15;
        const int i0 = (t >> 4) * 2;       // 0..62
        float a0 = c3, a1 = c3;
        const float* a2row = &sA2t[j * 68];
        const float* b0r = &sA1[(i0 + 0) * 68];
        const float* b1r = &sA1[(i0 + 1) * 68];
        #pragma unroll 4
        for (int kk = 0; kk < 64; kk += 4) {
            float4 va = *(const float4*)&a2row[kk];
            float4 vv = *(const float4*)&sV2[kk];
            float4 q0 = *(const float4*)&b0r[kk];
            float4 q1 = *(const float4*)&b1r[kk];
            a0 = fmaf(gelu_f(q0.x - va.x), vv.x, a0);
            a1 = fmaf(gelu_f(q1.x - va.x), vv.x, a1);
            a0 = fmaf(gelu_f(q0.y - va.y), vv.y, a0);
            a1 = fmaf(gelu_f(q1.y - va.y), vv.y, a1);
            a0 = fmaf(gelu_f(q0.z - va.z), vv.z, a0);
            a1 = fmaf(gelu_f(q1.z - va.z), vv.z, a1);
            a0 = fmaf(gelu_f(q0.w - va.w), vv.w, a0);
            a1 = fmaf(gelu_f(q1.w - va.w), vv.w, a1);
        }
        *(float2*)&sSt[j * 68 + i0] = make_float2(a0, a1);
    }
    __syncthreads();                                   // I

    // ---- partial aggregation + (ih==0: b3 + residual), atomicAdd to out ----
    {
        const int jA = t >> 5;         // 0..15
        const int dA = t & 31;
        const int jg = jt * 16 + jA;
        const float msk = sAny[jg];
        if (jg < iN && msk != 0.f) {
            const float* strow = &sSt[jA * 68];
            float s0 = 0.f;
            #pragma unroll 4
            for (int i = 0; i < 64; i += 4) {
                float4 sv = *(const float4*)&strow[i];
                s0 = fmaf(sv.x, sX1[(i + 0) * 32 + dA], s0);
                s0 = fmaf(sv.y, sX1[(i + 1) * 32 + dA], s0);
                s0 = fmaf(sv.z, sX1[(i + 2) * 32 + dA], s0);
                s0 = fmaf(sv.w, sX1[(i + 3) * 32 + dA], s0);
            }
            const size_t ob = (size_t)bm * ND + jg * 32 + dA;
            float val = s0;
            if (ih == 0) val += b3[0] + x[ob];
            atomicAdd(&out[ob], val);
        }
    }
}

extern "C" void kernel_launch(void* const* d_in, const int* in_sizes, int n_in,
                              void* d_out, int out_size, void* d_ws, size_t ws_size,
                              hipStream_t stream) {
    (void)in_sizes; (void)n_in; (void)d_ws; (void)ws_size; (void)out_size;
    const float* x      = (const float*)d_in[0];
    const float* x_size = (const float*)d_in[1];
    const float* W1a    = (const float*)d_in[2];
    const float* b1a    = (const float*)d_in[3];
    const float* W1b    = (const float*)d_in[4];
    const float* b1b    = (const float*)d_in[5];
    const float* W2a    = (const float*)d_in[6];
    const float* b2a    = (const float*)d_in[7];
    const float* W2b    = (const float*)d_in[8];
    const float* b2b    = (const float*)d_in[9];
    const float* w3     = (const float*)d_in[10];
    const float* b3     = (const float*)d_in[11];
    float* out = (float*)d_out;

    fused6<<<dim3(512), dim3(512), 0, stream>>>(
        x, x_size, W1a, b1a, W1b, b1b, W2a, b2a, W2b, b2b, w3, b3, out);
}